// Round 3
// baseline (168.707 us; speedup 1.0000x reference)
//
#include <hip/hip_runtime.h>
#include <math.h>

// InfoNCE: features (4096, 2048, 4) fp32.
// g=1024 groups, ni=4, t=4, n=16 rows/group, c=2048.
// f[g, j, c] = features[g*4 + (j%4), c, j/4]  -> float4 at (b_row, c) holds
// elements of rows {0,4,8,12} + (j%4) for component t = j/4.
//
// K1: 4 blocks per group (grid 4096, 128 thr). Each block covers 512 c's:
//     16 float4 loads/thread, fully unrolled and hoisted (deep MLP), 136-entry
//     partial Gram in registers, 6-step butterfly, 2-wave LDS combine,
//     partial S (136 floats) -> d_ws.
// K2: 1 block per group: sum 4 partials -> S, normalize + InfoNCE epilogue ->
//     per-group loss sum.
// K3: reduce 1024 partial losses -> out = -sum/48.

#define NGROUP 1024
#define C 2048
#define NPAIR 136       // 16*17/2
#define SPLIT 4
#define CPB (C / SPLIT) // 512
#define ITER (CPB / 128) // 4

__device__ __forceinline__ constexpr int pair_idx(int i, int j) {
    return i * 16 - (i * (i - 1)) / 2 + (j - i);
}

__global__ __launch_bounds__(128, 2)
void infonce_partial_kernel(const float4* __restrict__ feats,
                            float* __restrict__ psum) {
    const int blk  = blockIdx.x;
    const int g    = blk >> 2;
    const int s    = blk & 3;
    const int tid  = threadIdx.x;
    const int lane = tid & 63;
    const int wid  = tid >> 6;

    const float4* base = feats + (size_t)g * 4 * C + s * CPB + tid;

    // hoist ALL loads: 16 independent global_load_dwordx4 in flight
    float4 v[ITER][4];
#pragma unroll
    for (int it = 0; it < ITER; ++it)
#pragma unroll
        for (int row = 0; row < 4; ++row)
            v[it][row] = base[row * C + it * 128];

    float acc[NPAIR];
#pragma unroll
    for (int p = 0; p < NPAIR; ++p) acc[p] = 0.f;

#pragma unroll
    for (int it = 0; it < ITER; ++it) {
        const float r[16] = { v[it][0].x, v[it][1].x, v[it][2].x, v[it][3].x,
                              v[it][0].y, v[it][1].y, v[it][2].y, v[it][3].y,
                              v[it][0].z, v[it][1].z, v[it][2].z, v[it][3].z,
                              v[it][0].w, v[it][1].w, v[it][2].w, v[it][3].w };
#pragma unroll
        for (int i = 0; i < 16; ++i)
#pragma unroll
            for (int j = i; j < 16; ++j)
                acc[pair_idx(i, j)] = fmaf(r[i], r[j], acc[pair_idx(i, j)]);
    }

    // wave butterfly: every lane ends with the wave total
#pragma unroll
    for (int p = 0; p < NPAIR; ++p) {
        float x = acc[p];
        x += __shfl_xor(x, 1);
        x += __shfl_xor(x, 2);
        x += __shfl_xor(x, 4);
        x += __shfl_xor(x, 8);
        x += __shfl_xor(x, 16);
        x += __shfl_xor(x, 32);
        acc[p] = x;
    }

    __shared__ float wsum[2][NPAIR];
#pragma unroll
    for (int p = 0; p < NPAIR; ++p) {
        if (lane == (p & 63)) wsum[wid][p] = acc[p];
    }
    __syncthreads();

    float* dst = psum + (size_t)blk * NPAIR;
    for (int p = tid; p < NPAIR; p += 128)
        dst[p] = wsum[0][p] + wsum[1][p];
}

__global__ __launch_bounds__(128)
void infonce_group_finish(const float* __restrict__ psum,
                          float* __restrict__ gloss) {
    const int g   = blockIdx.x;
    const int tid = threadIdx.x;

    __shared__ float S[16][17];
    __shared__ float rowloss[16];

    const float* p0 = psum + (size_t)(g * 4 + 0) * NPAIR;
    const float* p1 = psum + (size_t)(g * 4 + 1) * NPAIR;
    const float* p2 = psum + (size_t)(g * 4 + 2) * NPAIR;
    const float* p3 = psum + (size_t)(g * 4 + 3) * NPAIR;

    for (int p = tid; p < NPAIR; p += 128) {
        int i = 0, rem = p;
        while (rem >= 16 - i) { rem -= 16 - i; ++i; }
        const int j = i + rem;
        const float s = p0[p] + p1[p] + p2[p] + p3[p];
        S[i][j] = s;
        S[j][i] = s;
    }
    __syncthreads();

    if (tid < 16) {
        const int i = tid;
        const float inv_i = 1.0f / fmaxf(sqrtf(S[i][i]), 1e-12f);
        float logits_row[16];
        float expneg = 0.f;
#pragma unroll
        for (int j = 0; j < 16; ++j) {
            const float inv_j = 1.0f / fmaxf(sqrtf(S[j][j]), 1e-12f);
            const float cosv = S[i][j] * inv_i * inv_j;
            const float lg = cosv / 0.07f;
            logits_row[j] = lg;
            if ((j >> 2) != (i >> 2)) expneg += expf(lg);  // negatives
        }
        float sum = 0.f;
#pragma unroll
        for (int j = 0; j < 16; ++j) {
            if ((j >> 2) == (i >> 2) && j != i) {          // positives
                const float lg = logits_row[j];
                sum += lg - logf(expneg + expf(lg));
            }
        }
        rowloss[i] = sum;
    }
    __syncthreads();

    if (tid == 0) {
        float t = 0.f;
#pragma unroll
        for (int i = 0; i < 16; ++i) t += rowloss[i];
        gloss[g] = t;
    }
}

__global__ void infonce_final_reduce(const float* __restrict__ gloss,
                                     float* __restrict__ out) {
    const int tid = threadIdx.x;
    float s = 0.f;
    for (int i = tid; i < NGROUP; i += 256) s += gloss[i];
    s += __shfl_xor(s, 1);
    s += __shfl_xor(s, 2);
    s += __shfl_xor(s, 4);
    s += __shfl_xor(s, 8);
    s += __shfl_xor(s, 16);
    s += __shfl_xor(s, 32);
    __shared__ float ws[4];
    const int lane = tid & 63, wid = tid >> 6;
    if (lane == 0) ws[wid] = s;
    __syncthreads();
    if (tid == 0) {
        const float t = ws[0] + ws[1] + ws[2] + ws[3];
        out[0] = -t / 48.0f;
    }
}

extern "C" void kernel_launch(void* const* d_in, const int* in_sizes, int n_in,
                              void* d_out, int out_size, void* d_ws, size_t ws_size,
                              hipStream_t stream) {
    const float4* feats = (const float4*)d_in[0];
    float* psum  = (float*)d_ws;                        // 4096*136 floats
    float* gloss = psum + (size_t)NGROUP * SPLIT * NPAIR; // 1024 floats
    float* out   = (float*)d_out;

    infonce_partial_kernel<<<NGROUP * SPLIT, 128, 0, stream>>>(feats, psum);
    infonce_group_finish<<<NGROUP, 128, 0, stream>>>(psum, gloss);
    infonce_final_reduce<<<1, 256, 0, stream>>>(gloss, out);
}

// Round 4
// 63.356 us; speedup vs baseline: 2.6628x; 2.6628x over previous
//
#include <hip/hip_runtime.h>
#include <math.h>

// InfoNCE: features (4096, 2048, 4) fp32.
// g=1024 groups, ni=4, t=4, n=16 rows/group, c=2048.
// f[g, j, c] = features[g*4 + (j%4), c, j/4]  -> float4 at (b_row, c) holds
// elements of rows {0,4,8,12} + (j%4) for component t = j/4.
//
// Register-pressure-driven redesign (R3 post-mortem: 136 acc/thread spills
// at the 128-VGPR budget; WRITE_SIZE showed ~12 MB scratch traffic):
//   K1: grid 2048 (2 blocks/group, c-split), 128 thr = 2 waves.
//       Wave 0 accumulates pairs [0,68), wave 1 pairs [68,136).
//       Each wave streams the block's full 1024-c range (2nd wave's loads
//       hit L1/L2 -> HBM traffic unchanged). 68 acc + 16 load regs < 128
//       VGPR -> no spill, 4 waves/SIMD possible.
//   K2: per group: sum the 2 c-split partials -> S, normalize + InfoNCE
//       epilogue -> per-group loss sum.
//   K3: reduce 1024 partial losses -> out = -sum/48.

#define NGROUP 1024
#define C 2048
#define NPAIR 136        // 16*17/2
#define SPLIT 2
#define CPB (C / SPLIT)  // 1024
#define ITERS (CPB / 64) // 16 (per wave, one c per lane per iter)
#define HCUT 68          // pairs split: wave0 [0,68), wave1 [68,136)

__device__ __forceinline__ constexpr int pair_idx(int i, int j) {
    return i * 16 - (i * (i - 1)) / 2 + (j - i);
}

template <int LO, int HI>
__device__ __forceinline__ void accum_range(const float4* __restrict__ base,
                                            float* __restrict__ wsum) {
    float acc[HI - LO];
#pragma unroll
    for (int q = 0; q < HI - LO; ++q) acc[q] = 0.f;

    for (int it = 0; it < ITERS; ++it) {
        const float4 v0 = base[0 * C + it * 64];
        const float4 v1 = base[1 * C + it * 64];
        const float4 v2 = base[2 * C + it * 64];
        const float4 v3 = base[3 * C + it * 64];
        const float r[16] = { v0.x, v1.x, v2.x, v3.x,
                              v0.y, v1.y, v2.y, v3.y,
                              v0.z, v1.z, v2.z, v3.z,
                              v0.w, v1.w, v2.w, v3.w };
#pragma unroll
        for (int i = 0; i < 16; ++i)
#pragma unroll
            for (int j = i; j < 16; ++j) {
                const int p = pair_idx(i, j);   // constant after unroll
                if (p >= LO && p < HI)          // compile-time folded
                    acc[p - LO] = fmaf(r[i], r[j], acc[p - LO]);
            }
    }

    // wave butterfly: every lane ends with the wave total
#pragma unroll
    for (int q = 0; q < HI - LO; ++q) {
        float x = acc[q];
        x += __shfl_xor(x, 1);
        x += __shfl_xor(x, 2);
        x += __shfl_xor(x, 4);
        x += __shfl_xor(x, 8);
        x += __shfl_xor(x, 16);
        x += __shfl_xor(x, 32);
        acc[q] = x;
    }

    const int lane = threadIdx.x & 63;
#pragma unroll
    for (int q = 0; q < HI - LO; ++q) {
        if (lane == (q & 63)) wsum[LO + q] = acc[q];
    }
}

__global__ __launch_bounds__(128, 4)
void infonce_partial_kernel(const float4* __restrict__ feats,
                            float* __restrict__ psum) {
    const int blk  = blockIdx.x;
    const int g    = blk >> 1;
    const int s    = blk & 1;
    const int tid  = threadIdx.x;
    const int lane = tid & 63;
    const int wid  = tid >> 6;

    const float4* base = feats + (size_t)g * 4 * C + s * CPB + lane;

    __shared__ float wsum[NPAIR];

    if (wid == 0) accum_range<0, HCUT>(base, wsum);
    else          accum_range<HCUT, NPAIR>(base, wsum);
    __syncthreads();

    float* dst = psum + (size_t)blk * NPAIR;
    for (int p = tid; p < NPAIR; p += 128) dst[p] = wsum[p];
}

__global__ __launch_bounds__(128)
void infonce_group_finish(const float* __restrict__ psum,
                          float* __restrict__ gloss) {
    const int g   = blockIdx.x;
    const int tid = threadIdx.x;

    __shared__ float S[16][17];
    __shared__ float rowloss[16];

    const float* p0 = psum + (size_t)(g * 2 + 0) * NPAIR;
    const float* p1 = psum + (size_t)(g * 2 + 1) * NPAIR;

    for (int p = tid; p < NPAIR; p += 128) {
        int i = 0, rem = p;
        while (rem >= 16 - i) { rem -= 16 - i; ++i; }
        const int j = i + rem;
        const float s = p0[p] + p1[p];
        S[i][j] = s;
        S[j][i] = s;
    }
    __syncthreads();

    if (tid < 16) {
        const int i = tid;
        const float inv_i = 1.0f / fmaxf(sqrtf(S[i][i]), 1e-12f);
        float logits_row[16];
        float expneg = 0.f;
#pragma unroll
        for (int j = 0; j < 16; ++j) {
            const float inv_j = 1.0f / fmaxf(sqrtf(S[j][j]), 1e-12f);
            const float cosv = S[i][j] * inv_i * inv_j;
            const float lg = cosv / 0.07f;
            logits_row[j] = lg;
            if ((j >> 2) != (i >> 2)) expneg += expf(lg);  // negatives
        }
        float sum = 0.f;
#pragma unroll
        for (int j = 0; j < 16; ++j) {
            if ((j >> 2) == (i >> 2) && j != i) {          // positives
                const float lg = logits_row[j];
                sum += lg - logf(expneg + expf(lg));
            }
        }
        rowloss[i] = sum;
    }
    __syncthreads();

    if (tid == 0) {
        float t = 0.f;
#pragma unroll
        for (int i = 0; i < 16; ++i) t += rowloss[i];
        gloss[g] = t;
    }
}

__global__ void infonce_final_reduce(const float* __restrict__ gloss,
                                     float* __restrict__ out) {
    const int tid = threadIdx.x;
    float s = 0.f;
    for (int i = tid; i < NGROUP; i += 256) s += gloss[i];
    s += __shfl_xor(s, 1);
    s += __shfl_xor(s, 2);
    s += __shfl_xor(s, 4);
    s += __shfl_xor(s, 8);
    s += __shfl_xor(s, 16);
    s += __shfl_xor(s, 32);
    __shared__ float ws[4];
    const int lane = tid & 63, wid = tid >> 6;
    if (lane == 0) ws[wid] = s;
    __syncthreads();
    if (tid == 0) {
        const float t = ws[0] + ws[1] + ws[2] + ws[3];
        out[0] = -t / 48.0f;
    }
}

extern "C" void kernel_launch(void* const* d_in, const int* in_sizes, int n_in,
                              void* d_out, int out_size, void* d_ws, size_t ws_size,
                              hipStream_t stream) {
    const float4* feats = (const float4*)d_in[0];
    float* psum  = (float*)d_ws;                          // 2048*136 floats
    float* gloss = psum + (size_t)NGROUP * SPLIT * NPAIR; // 1024 floats
    float* out   = (float*)d_out;

    infonce_partial_kernel<<<NGROUP * SPLIT, 128, 0, stream>>>(feats, psum);
    infonce_group_finish<<<NGROUP, 128, 0, stream>>>(psum, gloss);
    infonce_final_reduce<<<1, 256, 0, stream>>>(gloss, out);
}